// Round 2
// baseline (5705.046 us; speedup 1.0000x reference)
//
#include <hip/hip_runtime.h>
#include <hip/hip_bf16.h>
#include <stdint.h>

#define DEV __device__ __forceinline__

typedef __attribute__((ext_vector_type(8))) short short8;   // 8 bf16 (4 VGPRs)
typedef __attribute__((ext_vector_type(4))) float floatx4;  // MFMA acc

DEV unsigned short f2bf(float f) {  // round-to-nearest-even fp32 -> bf16
  union { float f; unsigned u; } v; v.f = f;
  return (unsigned short)((v.u + 0x7fffu + ((v.u >> 16) & 1u)) >> 16);
}
DEV float bf2f(unsigned short s) {
  union { unsigned u; float f; } v; v.u = ((unsigned)s) << 16; return v.f;
}
DEV float sigmoid_f(float x) { return 1.0f / (1.0f + __expf(-x)); }
DEV float tanh_f(float x) { return 1.0f - 2.0f / (__expf(2.0f * x) + 1.0f); }

// async global->LDS, 16B per lane; LDS dest = wave-uniform base + lane*16
DEV void glds16(const unsigned short* g, unsigned short* l) {
  __builtin_amdgcn_global_load_lds(
      (const __attribute__((address_space(1))) unsigned int*)g,
      (__attribute__((address_space(3))) unsigned int*)l, 16, 0, 0);
}

// ---------------------------------------------------------------------------
// Device-scope grid barrier (sense-reversal, single counter + generation).
// bar[0] = arrive counter, bar[1] = generation. Zeroed host-side per launch.
// Release: entry __syncthreads drains each WG's stores to L2 (vmcnt(0)),
// thread0 __threadfence() writes back L2 (agent release). Acquire: thread0
// __threadfence() after spin invalidates L1/L2 for its CU (1 WG/CU -> covers
// the whole WG); exit __syncthreads orders it for all waves.
// ---------------------------------------------------------------------------
DEV void gridbar(unsigned* bar, unsigned nwg) {
  __syncthreads();
  if (threadIdx.x == 0) {
    __threadfence();
    const unsigned g =
        __hip_atomic_load(bar + 1, __ATOMIC_RELAXED, __HIP_MEMORY_SCOPE_AGENT);
    const unsigned old =
        __hip_atomic_fetch_add(bar, 1u, __ATOMIC_ACQ_REL, __HIP_MEMORY_SCOPE_AGENT);
    if (old == nwg - 1u) {
      __hip_atomic_store(bar, 0u, __ATOMIC_RELAXED, __HIP_MEMORY_SCOPE_AGENT);
      __hip_atomic_store(bar + 1, g + 1u, __ATOMIC_RELEASE, __HIP_MEMORY_SCOPE_AGENT);
    } else {
      while (__hip_atomic_load(bar + 1, __ATOMIC_RELAXED, __HIP_MEMORY_SCOPE_AGENT) == g)
        __builtin_amdgcn_s_sleep(2);
    }
    __threadfence();
  }
  __syncthreads();
}

// ---------------------------------------------------------------------------
// Persistent recurrence kernel: 256 WGs x 256 threads, 1 WG/CU.
// WG (m = wg>>5, n = wg&31): rows R0 = 32m (h rows), phase A cols 64n of the
// 2048 gate dims, phase B cols 32n of the 1024 cand dims.
// Phase A: [256x2048] = hbf @ [Whu;Whr]^T, tile 32x64, BK=128, glds dbuf.
// Phase B: [256x1024] = rhbf @ Wh^T, tile 32x32.
// Weights per WG are fixed across steps -> L2-resident (persistent mapping).
// ---------------------------------------------------------------------------
__global__ __launch_bounds__(256, 1) void k_recur(
    const unsigned short* __restrict__ XPur, const unsigned short* __restrict__ Whh,
    float* __restrict__ out, float* __restrict__ h, unsigned short* __restrict__ hbf,
    float* __restrict__ u, unsigned short* __restrict__ rhbf,
    const float* __restrict__ b_h, unsigned* __restrict__ bar) {
  __shared__ __align__(16) unsigned short lds[2 * 12288];  // 48 KB dbuf
  const int tid = threadIdx.x;
  const int w = tid >> 6, l = tid & 63;
  const int l15 = l & 15, l4 = l >> 4;
  const int wm = w >> 1, wn = w & 1;
  const int wg = blockIdx.x;
  const int m = wg >> 5, n = wg & 31;
  const int R0 = m * 32;
  const floatx4 z = {0.f, 0.f, 0.f, 0.f};
  const unsigned short* Wh = Whh + 2048 * 1024;

  // ---- h0 = tanh(XPi[t=0]) (k_pre staged XPi+b_i into out[b][t][:]) ----
  {
    const int col = n * 32 + (tid & 31);
    const int rb = R0 + (tid >> 5);
#pragma unroll
    for (int r4 = 0; r4 < 4; r4++) {
      const int row = rb + r4 * 8;
      const size_t oidx = (size_t)row * 65536 + col;
      const float v = tanh_f(out[oidx]);
      out[oidx] = v;
      h[row * 1024 + col] = v;
      hbf[row * 1024 + col] = f2bf(v);
    }
  }
  gridbar(bar, 256);

  for (int t = 1; t < 64; t++) {
    // ================= phase A: gates =================
    {
      const unsigned short* XPt = XPur + (size_t)t * 524288;
      const int C0 = n * 64;
      // epilogue-operand prefetch (latency hides under staging)
      unsigned short xp[2][4];
      float hh[2][4];
#pragma unroll
      for (int j = 0; j < 2; j++)
#pragma unroll
        for (int r = 0; r < 4; r++) {
          const int row = R0 + wm * 16 + l4 * 4 + r;
          const int c = C0 + wn * 32 + j * 16 + l15;
          xp[j][r] = XPt[(size_t)row * 2048 + c];
        }
      if (C0 >= 1024) {
#pragma unroll
        for (int j = 0; j < 2; j++)
#pragma unroll
          for (int r = 0; r < 4; r++) {
            const int row = R0 + wm * 16 + l4 * 4 + r;
            const int c = C0 + wn * 32 + j * 16 + l15 - 1024;
            hh[j][r] = h[row * 1024 + c];
          }
      }
      floatx4 acc[2];
      acc[0] = z; acc[1] = z;
      // staging: wave w stages all chunks with ksub==w (A: mf 0..1, B: nf 0..3)
      const int kl = w * 32 + l4 * 8;  // k offset within BK=128 chunk
#define STAGE_A(k0, buf)                                                        \
  {                                                                             \
    unsigned short* lb = lds + (buf) * 12288;                                   \
    const unsigned short* ga = hbf + (size_t)(R0 + l15) * 1024 + (k0) + kl;     \
    glds16(ga, lb + (w * 2 + 0) * 512);                                         \
    glds16(ga + 16 * 1024, lb + (w * 2 + 1) * 512);                             \
    const unsigned short* gb = Whh + (size_t)(C0 + l15) * 1024 + (k0) + kl;     \
    glds16(gb, lb + 4096 + (w * 4 + 0) * 512);                                  \
    glds16(gb + 16 * 1024, lb + 4096 + (w * 4 + 1) * 512);                      \
    glds16(gb + 32 * 1024, lb + 4096 + (w * 4 + 2) * 512);                      \
    glds16(gb + 48 * 1024, lb + 4096 + (w * 4 + 3) * 512);                      \
  }
      STAGE_A(0, 0)
      for (int k0 = 0; k0 < 1024; k0 += 128) {
        const int buf = (k0 >> 7) & 1;
        __syncthreads();  // drains vmcnt(0): staged buf ready
        if (k0 + 128 < 1024) STAGE_A(k0 + 128, buf ^ 1)
        const unsigned short* lb = lds + buf * 12288;
#pragma unroll
        for (int ks = 0; ks < 4; ks++) {
          const short8 a = *(const short8*)(lb + (ks * 2 + wm) * 512 + l * 8);
#pragma unroll
          for (int j = 0; j < 2; j++) {
            const short8 b = *(const short8*)(lb + 4096 + (ks * 4 + wn * 2 + j) * 512 + l * 8);
            acc[j] = __builtin_amdgcn_mfma_f32_16x16x32_bf16(a, b, acc[j], 0, 0, 0);
          }
        }
      }
      if (C0 < 1024) {  // u = sigmoid(pre)  (wave-uniform branch: n<16)
#pragma unroll
        for (int j = 0; j < 2; j++)
#pragma unroll
          for (int r = 0; r < 4; r++) {
            const int row = R0 + wm * 16 + l4 * 4 + r;
            const int c = C0 + wn * 32 + j * 16 + l15;
            u[row * 1024 + c] = sigmoid_f(acc[j][r] + bf2f(xp[j][r]));
          }
      } else {  // r-gate -> rhbf = bf16(sigmoid(pre) * h)
#pragma unroll
        for (int j = 0; j < 2; j++)
#pragma unroll
          for (int r = 0; r < 4; r++) {
            const int row = R0 + wm * 16 + l4 * 4 + r;
            const int c = C0 + wn * 32 + j * 16 + l15 - 1024;
            const float rr = sigmoid_f(acc[j][r] + bf2f(xp[j][r]));
            rhbf[row * 1024 + c] = f2bf(rr * hh[j][r]);
          }
      }
    }
    gridbar(bar, 256);

    // ================= phase B: candidate + state update =================
    {
      const int C0B = n * 32;
      const int colB = C0B + wn * 16 + l15;
      float xpi[4], uu[4], hp[4];
#pragma unroll
      for (int r = 0; r < 4; r++) {
        const int row = R0 + wm * 16 + l4 * 4 + r;
        xpi[r] = out[((size_t)row * 64 + t) * 1024 + colB];
        uu[r] = u[row * 1024 + colB];
        hp[r] = h[row * 1024 + colB];
      }
      const float bhv = b_h[colB];
      floatx4 acc = z;
      const int kl = w * 32 + l4 * 8;
#define STAGE_B(k0, buf)                                                        \
  {                                                                             \
    unsigned short* lb = lds + (buf) * 12288;                                   \
    const unsigned short* ga = rhbf + (size_t)(R0 + l15) * 1024 + (k0) + kl;    \
    glds16(ga, lb + (w * 2 + 0) * 512);                                         \
    glds16(ga + 16 * 1024, lb + (w * 2 + 1) * 512);                             \
    const unsigned short* gb = Wh + (size_t)(C0B + l15) * 1024 + (k0) + kl;     \
    glds16(gb, lb + 4096 + (w * 2 + 0) * 512);                                  \
    glds16(gb + 16 * 1024, lb + 4096 + (w * 2 + 1) * 512);                      \
  }
      STAGE_B(0, 0)
      for (int k0 = 0; k0 < 1024; k0 += 128) {
        const int buf = (k0 >> 7) & 1;
        __syncthreads();
        if (k0 + 128 < 1024) STAGE_B(k0 + 128, buf ^ 1)
        const unsigned short* lb = lds + buf * 12288;
#pragma unroll
        for (int ks = 0; ks < 4; ks++) {
          const short8 a = *(const short8*)(lb + (ks * 2 + wm) * 512 + l * 8);
          const short8 b = *(const short8*)(lb + 4096 + (ks * 2 + wn) * 512 + l * 8);
          acc = __builtin_amdgcn_mfma_f32_16x16x32_bf16(a, b, acc, 0, 0, 0);
        }
      }
#pragma unroll
      for (int r = 0; r < 4; r++) {
        const int row = R0 + wm * 16 + l4 * 4 + r;
        const float cand = tanh_f(acc[r] + xpi[r] + bhv);
        const float hn = uu[r] * hp[r] + (1.0f - uu[r]) * cand;
        out[((size_t)row * 64 + t) * 1024 + colB] = hn;
        h[row * 1024 + colB] = hn;
        hbf[row * 1024 + colB] = f2bf(hn);
      }
    }
    gridbar(bar, 256);
  }
}

// ---------------------------------------------------------------------------
// Big hoisted GEMM for x-projections (unchanged from round 1).
// ---------------------------------------------------------------------------
DEV void gemm128(const unsigned short* __restrict__ A,
                 const unsigned short* __restrict__ B,
                 int tileM, int tileN, floatx4 (&acc)[4][4]) {
  __shared__ __align__(16) unsigned short lds[2][2][4096];
  const int tid = threadIdx.x;
  const int w = tid >> 6, l = tid & 63;
  const int l15 = l & 15, l4 = l >> 4;
  const int wm = w >> 1, wn = w & 1;

  floatx4 z = {0.f, 0.f, 0.f, 0.f};
#pragma unroll
  for (int i = 0; i < 4; i++)
#pragma unroll
    for (int j = 0; j < 4; j++) acc[i][j] = z;

  const unsigned short* ga0 = A + (size_t)(tileM + w * 16 + l15) * 1024 + l4 * 8;
  const unsigned short* ga1 = ga0 + 64 * 1024;
  const unsigned short* gb0 = B + (size_t)(tileN + w * 16 + l15) * 1024 + l4 * 8;
  const unsigned short* gb1 = gb0 + 64 * 1024;

  glds16(ga0, &lds[0][0][w * 512]);
  glds16(ga1, &lds[0][0][(w + 4) * 512]);
  glds16(gb0, &lds[0][1][w * 512]);
  glds16(gb1, &lds[0][1][(w + 4) * 512]);

#pragma unroll 2
  for (int k0 = 0; k0 < 1024; k0 += 32) {
    const int buf = (k0 >> 5) & 1;
    __syncthreads();
    const int kn = k0 + 32;
    if (kn < 1024) {
      const int nb = buf ^ 1;
      glds16(ga0 + kn, &lds[nb][0][w * 512]);
      glds16(ga1 + kn, &lds[nb][0][(w + 4) * 512]);
      glds16(gb0 + kn, &lds[nb][1][w * 512]);
      glds16(gb1 + kn, &lds[nb][1][(w + 4) * 512]);
    }
    short8 af[4], bfr[4];
    const unsigned short* lA = &lds[buf][0][wm * 2048];
    const unsigned short* lB = &lds[buf][1][wn * 2048];
#pragma unroll
    for (int i = 0; i < 4; i++) af[i] = *(const short8*)(lA + i * 512 + l * 8);
#pragma unroll
    for (int j = 0; j < 4; j++) bfr[j] = *(const short8*)(lB + j * 512 + l * 8);
#pragma unroll
    for (int i = 0; i < 4; i++)
#pragma unroll
      for (int j = 0; j < 4; j++)
        acc[i][j] = __builtin_amdgcn_mfma_f32_16x16x32_bf16(af[i], bfr[j], acc[i][j], 0, 0, 0);
  }
}

#define EPILOGUE_INDICES                                   \
  const int tid = threadIdx.x;                             \
  const int w = tid >> 6, l = tid & 63;                    \
  const int l15 = l & 15, l4 = l >> 4;                     \
  const int wm = w >> 1, wn = w & 1;                       \
  (void)w;

__global__ __launch_bounds__(256) void k_pre(
    const unsigned short* __restrict__ Xbf, const unsigned short* __restrict__ Wx,
    unsigned short* __restrict__ XPur, float* __restrict__ out,
    const float* __restrict__ b_iu, const float* __restrict__ b_hu,
    const float* __restrict__ b_ir, const float* __restrict__ b_hr,
    const float* __restrict__ b_i) {
  const int tileN = blockIdx.x * 128;
  const int tileM = blockIdx.y * 128;
  floatx4 acc[4][4];
  gemm128(Xbf, Wx, tileM, tileN, acc);
  EPILOGUE_INDICES
#pragma unroll
  for (int i = 0; i < 4; i++)
#pragma unroll
    for (int j = 0; j < 4; j++) {
      const int col = tileN + wn * 64 + j * 16 + l15;
      const int rbase = tileM + wm * 64 + i * 16 + l4 * 4;
#pragma unroll
      for (int r = 0; r < 4; r++) {
        const int row = rbase + r;
        const float v = acc[i][j][r];
        if (col < 2048) {
          const float bias = (col < 1024) ? (b_iu[col] + b_hu[col])
                                          : (b_ir[col - 1024] + b_hr[col - 1024]);
          const int b = row >> 6, t = row & 63;
          XPur[(size_t)((t << 8) | b) * 2048 + col] = f2bf(v + bias);
        } else {
          out[(size_t)row * 1024 + (col - 2048)] = v + b_i[col - 2048];
        }
      }
    }
}

// --------------------------- small helper kernels ---------------------------
__global__ __launch_bounds__(256) void k_conv_txt(const float* __restrict__ x,
                                                  unsigned short* __restrict__ y) {
  const int i = blockIdx.x * 256 + threadIdx.x;
  const float4 v = ((const float4*)x)[i];
  uint2 o;
  o.x = (unsigned)f2bf(v.x) | ((unsigned)f2bf(v.y) << 16);
  o.y = (unsigned)f2bf(v.z) | ((unsigned)f2bf(v.w) << 16);
  ((uint2*)y)[i] = o;
}

__global__ __launch_bounds__(256) void k_conv_w(
    const float* __restrict__ Wiu, const float* __restrict__ Wir, const float* __restrict__ Wi,
    const float* __restrict__ Whu, const float* __restrict__ Whr, const float* __restrict__ Wh,
    unsigned short* __restrict__ Wx, unsigned short* __restrict__ Whh) {
  const int idx = blockIdx.x * 256 + threadIdx.x;
  const int second = idx >= 786432;
  const int id = idx - (second ? 786432 : 0);
  const int n = id >> 8;
  const int kk = (id & 255) << 2;
  const int sel = n >> 10, r = n & 1023;
  const float* src;
  if (second) src = (sel == 0) ? Whu : (sel == 1) ? Whr : Wh;
  else        src = (sel == 0) ? Wiu : (sel == 1) ? Wir : Wi;
  const float4 v = *(const float4*)(src + (size_t)r * 1024 + kk);
  uint2 o;
  o.x = (unsigned)f2bf(v.x) | ((unsigned)f2bf(v.y) << 16);
  o.y = (unsigned)f2bf(v.z) | ((unsigned)f2bf(v.w) << 16);
  unsigned short* dst = second ? Whh : Wx;
  *(uint2*)(dst + (size_t)n * 1024 + kk) = o;
}

// ---------------------------------------------------------------------------
extern "C" void kernel_launch(void* const* d_in, const int* in_sizes, int n_in,
                              void* d_out, int out_size, void* d_ws, size_t ws_size,
                              hipStream_t stream) {
  const float* txt  = (const float*)d_in[0];
  const float* Wiu  = (const float*)d_in[1];
  const float* biu  = (const float*)d_in[2];
  const float* Whu  = (const float*)d_in[3];
  const float* bhu  = (const float*)d_in[4];
  const float* Wir  = (const float*)d_in[5];
  const float* bir  = (const float*)d_in[6];
  const float* Whr  = (const float*)d_in[7];
  const float* bhr  = (const float*)d_in[8];
  const float* Wi   = (const float*)d_in[9];
  const float* bi   = (const float*)d_in[10];
  const float* Wh   = (const float*)d_in[11];
  const float* bh   = (const float*)d_in[12];
  float* out = (float*)d_out;

  char* ws = (char*)d_ws;
  unsigned short* Xbf  = (unsigned short*)(ws);              //  32 MB
  unsigned short* Wx   = (unsigned short*)(ws + 33554432);   //   6 MB
  unsigned short* Whhc = (unsigned short*)(ws + 39845888);   //   6 MB (hu|hr|h)
  unsigned short* XPur = (unsigned short*)(ws + 46137344);   //  64 MB [64][256][2048]
  float*          hbuf = (float*)(ws + 113246208);           //   1 MB
  unsigned short* hbf  = (unsigned short*)(ws + 114294784);  // 0.5 MB
  float*          ubuf = (float*)(ws + 114819072);           //   1 MB
  unsigned short* rhbf = (unsigned short*)(ws + 115867648);  // 0.5 MB
  unsigned*       bar  = (unsigned*)(ws + 116391936);        // barrier (zeroed)

  hipMemsetAsync((void*)bar, 0, 256, stream);

  // 1) cast inputs to bf16
  k_conv_txt<<<16384, 256, 0, stream>>>(txt, Xbf);
  k_conv_w<<<6144, 256, 0, stream>>>(Wiu, Wir, Wi, Whu, Whr, Wh, Wx, Whhc);

  // 2) hoisted x-projections for all 64 steps
  k_pre<<<dim3(24, 128), 256, 0, stream>>>(Xbf, Wx, XPur, out, biu, bhu, bir, bhr, bi);

  // 3) persistent recurrence: h0 + 63 steps, grid barriers between phases.
  //    256 WGs x 256 thr on 256 CUs (1 WG/CU, always co-resident).
  k_recur<<<256, 256, 0, stream>>>(XPur, Whhc, out, hbuf, hbf, ubuf, rhbf, bh, bar);

  (void)in_sizes; (void)n_in; (void)out_size; (void)ws_size;
}

// Round 5
// 1401.878 us; speedup vs baseline: 4.0696x; 4.0696x over previous
//
#include <hip/hip_runtime.h>
#include <hip/hip_bf16.h>
#include <stdint.h>

#define DEV __device__ __forceinline__

typedef __attribute__((ext_vector_type(8))) short short8;   // 8 bf16 (4 VGPRs)
typedef __attribute__((ext_vector_type(4))) float floatx4;  // MFMA acc

DEV unsigned short f2bf(float f) {  // round-to-nearest-even fp32 -> bf16
  union { float f; unsigned u; } v; v.f = f;
  return (unsigned short)((v.u + 0x7fffu + ((v.u >> 16) & 1u)) >> 16);
}
DEV float bf2f(unsigned short s) {
  union { unsigned u; float f; } v; v.u = ((unsigned)s) << 16; return v.f;
}
DEV float sigmoid_f(float x) { return 1.0f / (1.0f + __expf(-x)); }
DEV float tanh_f(float x) { return 1.0f - 2.0f / (__expf(2.0f * x) + 1.0f); }

// async global->LDS, 16B per lane; compiler-tracked (drained by the vmcnt(0)
// the compiler emits before s_barrier). Normal cache policy.
DEV void glds16(const unsigned short* g, unsigned short* l) {
  __builtin_amdgcn_global_load_lds(
      (const __attribute__((address_space(1))) unsigned int*)g,
      (__attribute__((address_space(3))) unsigned int*)l, 16, 0, 0);
}

// Cross-WG visible store: bf16 pair packed to a dword, relaxed agent-scope
// atomic store. Compiler-lowered coherence bits (same path as the working
// barrier atomics) -> visible at the device coherence point on completion;
// relaxed -> no cache-maintenance fences emitted.
DEV void store_pair_coh(unsigned* p, unsigned v) {
  __hip_atomic_store(p, v, __ATOMIC_RELAXED, __HIP_MEMORY_SCOPE_AGENT);
}

// ---------------------------------------------------------------------------
// Per-group (32 WG) ticket barrier, step-indexed slots, relaxed agent atomics
// (no fences). Ordering: __syncthreads drains vmcnt(0) (all data stores
// complete & visible) before thread0 arrives; consumers load after the spin.
// ---------------------------------------------------------------------------
DEV void groupbar(unsigned* slot) {
  __syncthreads();  // emits s_waitcnt vmcnt(0) lgkmcnt(0) before s_barrier
  if (threadIdx.x == 0) {
    __hip_atomic_fetch_add(slot, 1u, __ATOMIC_RELAXED, __HIP_MEMORY_SCOPE_AGENT);
    while (__hip_atomic_load(slot, __ATOMIC_RELAXED, __HIP_MEMORY_SCOPE_AGENT) < 32u)
      __builtin_amdgcn_s_sleep(1);
  }
  __syncthreads();
}

// ---- staging helpers (fragment-order LDS: frag f at f*512 shorts, lane at
// +l*16B -> ds_read_b128 lane-linear, conflict-free) ------------------------
// Phase A chunk (BK=128): A=hbf[t-1] 32x128 (8 frags), Bu=Whu 32x128 (8),
// Br=Whr 32x128 (8). 24 KB/chunk. Wave w stages frags {2w,2w+1} of each.
DEV void stageA(const unsigned short* hbfPrev, const unsigned short* Whhc,
                unsigned short* lb, int R0, int C0B, int k0, int w, int l15, int l4) {
#pragma unroll
  for (int q = 0; q < 2; q++) {
    const int f = w * 2 + q;
    const int rg = f >> 2, kg = f & 3;
    const size_t kk = (size_t)k0 + kg * 32 + l4 * 8;
    glds16(hbfPrev + (size_t)(R0 + rg * 16 + l15) * 1024 + kk, lb + f * 512);
    glds16(Whhc + (size_t)(C0B + rg * 16 + l15) * 1024 + kk, lb + 4096 + f * 512);
    glds16(Whhc + (size_t)(1024 + C0B + rg * 16 + l15) * 1024 + kk, lb + 8192 + f * 512);
  }
}
// Phase B chunk (BK=256): A=rhbf[t] 32x256 (16 frags), B=Wh 32x256 (16).
// 32 KB/chunk. Wave w stages frags {4w..4w+3} of each.
DEV void stageB(const unsigned short* rhbfT, const unsigned short* WhT,
                unsigned short* lb, int R0, int C0B, int k0, int w, int l15, int l4) {
#pragma unroll
  for (int q = 0; q < 4; q++) {
    const int f = w * 4 + q;
    const int rg = f >> 3, kg = f & 7;
    const size_t kk = (size_t)k0 + kg * 32 + l4 * 8;
    glds16(rhbfT + (size_t)(R0 + rg * 16 + l15) * 1024 + kk, lb + f * 512);
    glds16(WhT + (size_t)(C0B + rg * 16 + l15) * 1024 + kk, lb + 8192 + f * 512);
  }
}

// ---------------------------------------------------------------------------
// Persistent recurrence: 256 WGs x 256 thr, 1 WG/CU. n = blockIdx&31 (output
// col slice 32n, and n%8 = XCD so weight slices are XCD-local & L2-resident),
// g = blockIdx>>5 (batch rows 32g..+31). h is WG-private (owner-only access).
// Cross-WG state: hbf ring (64 slices, write-once) + rhbf ring (16 slices;
// reuse separated by ~16x6MB per-XCD L2 traffic >> 4MiB -> evicted).
// u-gate computed in phase A, carried to phase B in registers (no memory).
// ---------------------------------------------------------------------------
__global__ __launch_bounds__(256, 1) void k_recur(
    const unsigned short* __restrict__ XPur, const unsigned short* __restrict__ Whhc,
    float* __restrict__ out, float* __restrict__ h,
    unsigned short* __restrict__ hbfR, unsigned short* __restrict__ rhbfR,
    const float* __restrict__ b_h, unsigned* __restrict__ bar) {
  __shared__ __align__(16) unsigned short lds[32768];  // 64 KB
  const int tid = threadIdx.x;
  const int w = tid >> 6, l = tid & 63;
  const int l15 = l & 15, l4 = l >> 4;
  const int wm = w >> 1, wn = w & 1;
  const int n = blockIdx.x & 31, g = blockIdx.x >> 5;
  const int R0 = g * 32, C0B = n * 32;
  unsigned* slots = bar + g * 128;
  unsigned* hbfRu = (unsigned*)hbfR;
  const unsigned short* WhT = Whhc + (size_t)2048 * 1024;
  const floatx4 z = {0.f, 0.f, 0.f, 0.f};

  // ---- h0 = tanh(XPi[t=0]); k_pre staged XPi+b_i into out[b][0][:] ----
  {
    const int col = C0B + (tid & 31);
    const int rb = R0 + (tid >> 5);
#pragma unroll
    for (int r4 = 0; r4 < 4; r4++) {
      const int row = rb + r4 * 8;
      const size_t oidx = (size_t)row * 65536 + col;
      const float v = tanh_f(out[oidx]);
      out[oidx] = v;
      h[row * 1024 + col] = v;  // private: only WG n touches cols 32n..+31
      const unsigned mv = (unsigned)f2bf(v);
      const unsigned ov = (unsigned)__shfl_xor((int)mv, 1, 64);
      if ((tid & 1) == 0)
        store_pair_coh(hbfRu + row * 512 + (col >> 1), mv | (ov << 16));
    }
  }
  groupbar(slots + 1);

  const int col = C0B + wn * 16 + l15;      // this wave's output col
  const int erow0 = R0 + wm * 16 + l4 * 4;  // C/D layout row base
  const float bhv = b_h[col];

  for (int t = 1; t < 64; t++) {
    const unsigned short* hbfPrev = hbfR + (size_t)(t - 1) * 262144;
    unsigned short* rhbfT = rhbfR + (size_t)(t & 15) * 262144;
    unsigned* rhbfTu = (unsigned*)rhbfT;

    // ========== phase A: u (kept in regs) and r -> rhbf[t] ==========
    float uu[4], hp[4];
    {
      const unsigned short* XPt = XPur + (size_t)t * 524288;
      unsigned short xpu[4], xpr[4];
#pragma unroll
      for (int r = 0; r < 4; r++) {
        xpu[r] = XPt[(size_t)(erow0 + r) * 2048 + col];
        xpr[r] = XPt[(size_t)(erow0 + r) * 2048 + 1024 + col];
        hp[r] = h[(erow0 + r) * 1024 + col];  // private, reused in phase B
      }
      floatx4 acc_u = z, acc_r = z;
      stageA(hbfPrev, Whhc, lds, R0, C0B, 0, w, l15, l4);
#pragma unroll
      for (int c = 0; c < 8; c++) {
        const int buf = c & 1;
        __syncthreads();  // vmcnt(0): chunk c staged
        if (c < 7) stageA(hbfPrev, Whhc, lds + (buf ^ 1) * 12288, R0, C0B, (c + 1) * 128, w, l15, l4);
        const unsigned short* lb = lds + buf * 12288;
#pragma unroll
        for (int kg = 0; kg < 4; kg++) {
          const short8 a = *(const short8*)(lb + (wm * 4 + kg) * 512 + l * 8);
          const short8 bu = *(const short8*)(lb + 4096 + (wn * 4 + kg) * 512 + l * 8);
          const short8 br = *(const short8*)(lb + 8192 + (wn * 4 + kg) * 512 + l * 8);
          acc_u = __builtin_amdgcn_mfma_f32_16x16x32_bf16(a, bu, acc_u, 0, 0, 0);
          acc_r = __builtin_amdgcn_mfma_f32_16x16x32_bf16(a, br, acc_r, 0, 0, 0);
        }
      }
#pragma unroll
      for (int r = 0; r < 4; r++) {
        uu[r] = sigmoid_f(acc_u[r] + bf2f(xpu[r]));
        const float rr = sigmoid_f(acc_r[r] + bf2f(xpr[r]));
        const unsigned mv = (unsigned)f2bf(rr * hp[r]);
        const unsigned ov = (unsigned)__shfl_xor((int)mv, 1, 64);
        if ((l & 1) == 0)
          store_pair_coh(rhbfTu + (erow0 + r) * 512 + (col >> 1), mv | (ov << 16));
      }
    }
    groupbar(slots + 2 * t);

    // ========== phase B: cand = tanh(rh@Wh + xpi + bh); update ==========
    {
      float xpi[4];
#pragma unroll
      for (int r = 0; r < 4; r++)
        xpi[r] = out[((size_t)(erow0 + r) * 64 + t) * 1024 + col];
      floatx4 acc_c = z;
      stageB(rhbfT, WhT, lds, R0, C0B, 0, w, l15, l4);
#pragma unroll
      for (int c = 0; c < 4; c++) {
        const int buf = c & 1;
        __syncthreads();
        if (c < 3) stageB(rhbfT, WhT, lds + (buf ^ 1) * 16384, R0, C0B, (c + 1) * 256, w, l15, l4);
        const unsigned short* lb = lds + buf * 16384;
#pragma unroll
        for (int kg = 0; kg < 8; kg++) {
          const short8 a = *(const short8*)(lb + (wm * 8 + kg) * 512 + l * 8);
          const short8 bc = *(const short8*)(lb + 8192 + (wn * 8 + kg) * 512 + l * 8);
          acc_c = __builtin_amdgcn_mfma_f32_16x16x32_bf16(a, bc, acc_c, 0, 0, 0);
        }
      }
      unsigned* hbfCu = hbfRu + (size_t)t * 131072;
#pragma unroll
      for (int r = 0; r < 4; r++) {
        const int row = erow0 + r;
        const float cand = tanh_f(acc_c[r] + xpi[r] + bhv);
        const float hn = uu[r] * hp[r] + (1.0f - uu[r]) * cand;
        out[((size_t)row * 64 + t) * 1024 + col] = hn;  // private
        h[row * 1024 + col] = hn;                       // private
        const unsigned mv = (unsigned)f2bf(hn);
        const unsigned ov = (unsigned)__shfl_xor((int)mv, 1, 64);
        if ((l & 1) == 0)
          store_pair_coh(hbfCu + row * 512 + (col >> 1), mv | (ov << 16));
      }
    }
    groupbar(slots + 2 * t + 1);
  }
}

// ---------------------------------------------------------------------------
// Hoisted x-projections GEMM (unchanged).
// ---------------------------------------------------------------------------
DEV void gemm128(const unsigned short* __restrict__ A,
                 const unsigned short* __restrict__ B,
                 int tileM, int tileN, floatx4 (&acc)[4][4]) {
  __shared__ __align__(16) unsigned short lds[2][2][4096];
  const int tid = threadIdx.x;
  const int w = tid >> 6, l = tid & 63;
  const int l15 = l & 15, l4 = l >> 4;
  const int wm = w >> 1, wn = w & 1;

  floatx4 z = {0.f, 0.f, 0.f, 0.f};
#pragma unroll
  for (int i = 0; i < 4; i++)
#pragma unroll
    for (int j = 0; j < 4; j++) acc[i][j] = z;

  const unsigned short* ga0 = A + (size_t)(tileM + w * 16 + l15) * 1024 + l4 * 8;
  const unsigned short* ga1 = ga0 + 64 * 1024;
  const unsigned short* gb0 = B + (size_t)(tileN + w * 16 + l15) * 1024 + l4 * 8;
  const unsigned short* gb1 = gb0 + 64 * 1024;

  glds16(ga0, &lds[0][0][w * 512]);
  glds16(ga1, &lds[0][0][(w + 4) * 512]);
  glds16(gb0, &lds[0][1][w * 512]);
  glds16(gb1, &lds[0][1][(w + 4) * 512]);

#pragma unroll 2
  for (int k0 = 0; k0 < 1024; k0 += 32) {
    const int buf = (k0 >> 5) & 1;
    __syncthreads();
    const int kn = k0 + 32;
    if (kn < 1024) {
      const int nb = buf ^ 1;
      glds16(ga0 + kn, &lds[nb][0][w * 512]);
      glds16(ga1 + kn, &lds[nb][0][(w + 4) * 512]);
      glds16(gb0 + kn, &lds[nb][1][w * 512]);
      glds16(gb1 + kn, &lds[nb][1][(w + 4) * 512]);
    }
    short8 af[4], bfr[4];
    const unsigned short* lA = &lds[buf][0][wm * 2048];
    const unsigned short* lB = &lds[buf][1][wn * 2048];
#pragma unroll
    for (int i = 0; i < 4; i++) af[i] = *(const short8*)(lA + i * 512 + l * 8);
#pragma unroll
    for (int j = 0; j < 4; j++) bfr[j] = *(const short8*)(lB + j * 512 + l * 8);
#pragma unroll
    for (int i = 0; i < 4; i++)
#pragma unroll
      for (int j = 0; j < 4; j++)
        acc[i][j] = __builtin_amdgcn_mfma_f32_16x16x32_bf16(af[i], bfr[j], acc[i][j], 0, 0, 0);
  }
}

__global__ __launch_bounds__(256) void k_pre(
    const unsigned short* __restrict__ Xbf, const unsigned short* __restrict__ Wx,
    unsigned short* __restrict__ XPur, float* __restrict__ out,
    const float* __restrict__ b_iu, const float* __restrict__ b_hu,
    const float* __restrict__ b_ir, const float* __restrict__ b_hr,
    const float* __restrict__ b_i) {
  const int tileN = blockIdx.x * 128;
  const int tileM = blockIdx.y * 128;
  floatx4 acc[4][4];
  gemm128(Xbf, Wx, tileM, tileN, acc);
  const int tid = threadIdx.x;
  const int l = tid & 63;
  const int l15 = l & 15, l4 = l >> 4;
  const int wm = (tid >> 6) >> 1, wn = (tid >> 6) & 1;
#pragma unroll
  for (int i = 0; i < 4; i++)
#pragma unroll
    for (int j = 0; j < 4; j++) {
      const int col = tileN + wn * 64 + j * 16 + l15;
      const int rbase = tileM + wm * 64 + i * 16 + l4 * 4;
#pragma unroll
      for (int r = 0; r < 4; r++) {
        const int row = rbase + r;
        const float v = acc[i][j][r];
        if (col < 2048) {
          const float bias = (col < 1024) ? (b_iu[col] + b_hu[col])
                                          : (b_ir[col - 1024] + b_hr[col - 1024]);
          const int b = row >> 6, t = row & 63;
          XPur[(size_t)((t << 8) | b) * 2048 + col] = f2bf(v + bias);
        } else {
          out[(size_t)row * 1024 + (col - 2048)] = v + b_i[col - 2048];
        }
      }
    }
}

// --------------------------- small helper kernels ---------------------------
__global__ __launch_bounds__(256) void k_conv_txt(const float* __restrict__ x,
                                                  unsigned short* __restrict__ y) {
  const int i = blockIdx.x * 256 + threadIdx.x;
  const float4 v = ((const float4*)x)[i];
  uint2 o;
  o.x = (unsigned)f2bf(v.x) | ((unsigned)f2bf(v.y) << 16);
  o.y = (unsigned)f2bf(v.z) | ((unsigned)f2bf(v.w) << 16);
  ((uint2*)y)[i] = o;
}

__global__ __launch_bounds__(256) void k_conv_w(
    const float* __restrict__ Wiu, const float* __restrict__ Wir, const float* __restrict__ Wi,
    const float* __restrict__ Whu, const float* __restrict__ Whr, const float* __restrict__ Wh,
    unsigned short* __restrict__ Wx, unsigned short* __restrict__ Whh) {
  const int idx = blockIdx.x * 256 + threadIdx.x;
  const int second = idx >= 786432;
  const int id = idx - (second ? 786432 : 0);
  const int n = id >> 8;
  const int kk = (id & 255) << 2;
  const int sel = n >> 10, r = n & 1023;
  const float* src;
  if (second) src = (sel == 0) ? Whu : (sel == 1) ? Whr : Wh;
  else        src = (sel == 0) ? Wiu : (sel == 1) ? Wir : Wi;
  const float4 v = *(const float4*)(src + (size_t)r * 1024 + kk);
  uint2 o;
  o.x = (unsigned)f2bf(v.x) | ((unsigned)f2bf(v.y) << 16);
  o.y = (unsigned)f2bf(v.z) | ((unsigned)f2bf(v.w) << 16);
  unsigned short* dst = second ? Whh : Wx;
  *(uint2*)(dst + (size_t)n * 1024 + kk) = o;
}

// ---------------------------------------------------------------------------
extern "C" void kernel_launch(void* const* d_in, const int* in_sizes, int n_in,
                              void* d_out, int out_size, void* d_ws, size_t ws_size,
                              hipStream_t stream) {
  const float* txt  = (const float*)d_in[0];
  const float* Wiu  = (const float*)d_in[1];
  const float* biu  = (const float*)d_in[2];
  const float* Whu  = (const float*)d_in[3];
  const float* bhu  = (const float*)d_in[4];
  const float* Wir  = (const float*)d_in[5];
  const float* bir  = (const float*)d_in[6];
  const float* Whr  = (const float*)d_in[7];
  const float* bhr  = (const float*)d_in[8];
  const float* Wi   = (const float*)d_in[9];
  const float* bi   = (const float*)d_in[10];
  const float* Wh   = (const float*)d_in[11];
  const float* bh   = (const float*)d_in[12];
  float* out = (float*)d_out;

  char* ws = (char*)d_ws;
  unsigned short* Xbf  = (unsigned short*)(ws);              // 32 MB; reused as hbf ring
  unsigned short* hbfR = Xbf;                                // [64][256][1024] bf16 (write-once per slice)
  unsigned short* Wx   = (unsigned short*)(ws + 33554432);   //  6 MB
  unsigned short* Whhc = (unsigned short*)(ws + 39845888);   //  6 MB (Whu|Whr|Wh)
  unsigned short* XPur = (unsigned short*)(ws + 46137344);   // 64 MB [64][256][2048]
  float*          hbuf = (float*)(ws + 113246208);           //  1 MB (WG-private fp32 h)
  unsigned short* rhbfR= (unsigned short*)(ws + 114294784);  //  8 MB [16][256][1024]
  unsigned*       bar  = (unsigned*)(ws + 122683392);        //  4 KB ticket slots

  hipMemsetAsync((void*)bar, 0, 8 * 128 * 4, stream);

  k_conv_txt<<<16384, 256, 0, stream>>>(txt, Xbf);
  k_conv_w<<<6144, 256, 0, stream>>>(Wiu, Wir, Wi, Whu, Whr, Wh, Wx, Whhc);

  k_pre<<<dim3(24, 128), 256, 0, stream>>>(Xbf, Wx, XPur, out, biu, bhu, bir, bhr, bi);

  // persistent recurrence: write-once rings + relaxed agent-scope atomic
  // stores for cross-WG state; all loads compiler-tracked & normally cached.
  k_recur<<<256, 256, 0, stream>>>(XPur, Whhc, out, hbuf, hbfR, rhbfR, bh, bar);

  (void)in_sizes; (void)n_in; (void)out_size; (void)ws_size;
}